// Round 7
// baseline (159.903 us; speedup 1.0000x reference)
//
#include <hip/hip_runtime.h>

#define HW 4096
#define CCH 128
#define NB 4

typedef short bf16x8 __attribute__((ext_vector_type(8)));
typedef float f32x4 __attribute__((ext_vector_type(4)));

__device__ __forceinline__ unsigned short f2bf(float f){
  union { float fv; unsigned u; } v; v.fv = f;
  unsigned r = v.u + 0x7fffu + ((v.u >> 16) & 1u);
  return (unsigned short)(r >> 16);
}
__device__ __forceinline__ float bf2f(unsigned short u){
  return __uint_as_float(((unsigned)u) << 16);
}
__device__ __forceinline__ f32x4 mfma16(bf16x8 a, bf16x8 b, f32x4 c){
  return __builtin_amdgcn_mfma_f32_16x16x32_bf16(a, b, c, 0, 0, 0);
}
// async global->LDS, 16B/lane; LDS dest = wave-uniform base + lane*16
__device__ __forceinline__ void gll16(const void* g, void* l){
  __builtin_amdgcn_global_load_lds(
      (const __attribute__((address_space(1))) unsigned*)g,
      (__attribute__((address_space(3))) unsigned*)l, 16, 0, 0);
}

// ---------- Kernel A: group-norm stats + weight fp32->bf16 prep ----------
__global__ __launch_bounds__(256) void gn_stats_k(const float* __restrict__ x,
    float* __restrict__ stats,
    const float* __restrict__ wq, const float* __restrict__ wk,
    const float* __restrict__ wv, const float* __restrict__ wp,
    unsigned short* __restrict__ wqb, unsigned short* __restrict__ wkb,
    unsigned short* __restrict__ wvb, unsigned short* __restrict__ wpb){
  int tid = threadIdx.x;
  if (tid < 128){
    int f4 = blockIdx.x * 128 + tid;
    int m = f4 >> 12, e = f4 & 4095;
    const float* s4 = (m == 0) ? wq : ((m == 1) ? wk : ((m == 2) ? wv : wp));
    unsigned short* d4 = (m == 0) ? wqb : ((m == 1) ? wkb : ((m == 2) ? wvb : wpb));
    float4 v = *(const float4*)(s4 + e * 4);
    ushort4 b; b.x = f2bf(v.x); b.y = f2bf(v.y); b.z = f2bf(v.z); b.w = f2bf(v.w);
    *(ushort4*)(d4 + e * 4) = b;
  }
  int gid = blockIdx.x;
  const float4* p = (const float4*)(x + (size_t)gid * 16384);
  float s = 0.f, q = 0.f;
  #pragma unroll
  for (int i = 0; i < 16; i++){
    float4 v = p[tid + 256 * i];
    s += v.x + v.y + v.z + v.w;
    q += v.x * v.x + v.y * v.y + v.z * v.z + v.w * v.w;
  }
  #pragma unroll
  for (int d = 1; d < 64; d <<= 1){ s += __shfl_xor(s, d); q += __shfl_xor(q, d); }
  __shared__ float red[8];
  int w = tid >> 6;
  if ((tid & 63) == 0){ red[2 * w] = s; red[2 * w + 1] = q; }
  __syncthreads();
  if (tid == 0){
    float S = red[0] + red[2] + red[4] + red[6];
    float Q = red[1] + red[3] + red[5] + red[7];
    float mean = S * (1.f / 16384.f);
    float var  = Q * (1.f / 16384.f) - mean * mean;
    stats[2 * gid]     = mean;
    stats[2 * gid + 1] = rsqrtf(var + 1e-5f);
  }
}

// ---------- Kernel C: fused GN-apply + QKV projection ----------
// grid (64, NB, 3): block reads x tile directly, applies GN inline, builds
// swizzled bf16 hA in LDS (no ht global roundtrip), then one matmul.
__global__ __launch_bounds__(256, 3) void gnqkv_k(const float* __restrict__ x,
    const float* __restrict__ stats, const float* __restrict__ sc,
    const float* __restrict__ bi,
    const unsigned short* __restrict__ wqb, const unsigned short* __restrict__ wkb,
    const unsigned short* __restrict__ wvb,
    const float* __restrict__ bq, const float* __restrict__ bk,
    const float* __restrict__ bv,
    unsigned short* __restrict__ Qg, unsigned short* __restrict__ Kg,
    unsigned short* __restrict__ Vt){
  int n = blockIdx.y, l0 = blockIdx.x * 64, m = blockIdx.z, tid = threadIdx.x;
  int w = tid >> 6, lane = tid & 63, l15 = lane & 15, g = lane >> 4;
  __shared__ __align__(16) char lds[49152];
  char* hA = lds;            // 16KB [64 rows(l) x 256B(c)], slot s holds c-chunk s^(l&15)
  char* WB = lds + 16384;    // 32KB [128 rows x 256B], slot s holds chunk s^(row&15)
  const unsigned short* wsrc = (m == 0) ? wqb : ((m == 1) ? wkb : wvb);
  const float* bsrc = (m == 0) ? bq : ((m == 1) ? bk : bv);
  // issue weight glls first (latency hides under the x transform)
  {
    const char* wb2 = (const char*)wsrc;
    #pragma unroll
    for (int i = 0; i < 8; i++){
      int T = (8 * w + i) * 64 + lane;
      int row = T >> 4, c16 = (T & 15) ^ (row & 15);
      gll16(wb2 + row * 256 + c16 * 16, WB + (8 * w + i) * 1024);
    }
  }
  // x tile -> GN -> bf16 -> swizzled hA
  #pragma unroll
  for (int i = 0; i < 8; i++){
    int F = tid + 256 * i;           // float4 id, 2048 total
    int c = F >> 4, l4 = F & 15;     // c-row, float4 within row (l = 4*l4..)
    float4 v = *(const float4*)&x[((size_t)(n * CCH + c)) * HW + l0 + l4 * 4];
    int grp = n * 32 + (c >> 2);
    float mean = stats[2 * grp], rstd = stats[2 * grp + 1];
    float scl = rstd * sc[c];
    float off = bi[c] - mean * scl;
    float r0 = v.x * scl + off, r1 = v.y * scl + off;
    float r2 = v.z * scl + off, r3 = v.w * scl + off;
    int slotbase = ((c >> 3) << 4) ^ 0;  // slot depends on l too
    (void)slotbase;
    #pragma unroll
    for (int j = 0; j < 4; j++){
      int l = l4 * 4 + j;
      float rv = (j == 0) ? r0 : ((j == 1) ? r1 : ((j == 2) ? r2 : r3));
      int slot = (c >> 3) ^ (l & 15);
      *(unsigned short*)(hA + l * 256 + slot * 16 + ((c & 7) << 1)) = f2bf(rv);
    }
  }
  __syncthreads();
  bf16x8 a[4];
  #pragma unroll
  for (int kc = 0; kc < 4; kc++)
    a[kc] = *(const bf16x8*)(hA + (16 * w + l15) * 256 + ((4 * kc + g) ^ l15) * 16);
  f32x4 acc[8];
  #pragma unroll
  for (int ct = 0; ct < 8; ct++) acc[ct] = (f32x4)(0.f);
  #pragma unroll
  for (int ct = 0; ct < 8; ct++)
    #pragma unroll
    for (int kc = 0; kc < 4; kc++){
      bf16x8 bfr = *(const bf16x8*)(WB + (16 * ct + l15) * 256 + ((4 * kc + g) ^ l15) * 16);
      acc[ct] = mfma16(a[kc], bfr, acc[ct]);
    }
  __syncthreads();   // all waves done reading WB; reuse as output-stage LDS
  if (m < 2){
    float qs = (m == 0) ? 0.08838834764831845f : 1.0f;
    unsigned short* dst = (m == 0) ? Qg : Kg;
    unsigned short* os = (unsigned short*)(lds + 16384);  // [64][136]
    #pragma unroll
    for (int ct = 0; ct < 8; ct++){
      int o = 16 * ct + l15;
      float bias = bsrc[o];
      #pragma unroll
      for (int r = 0; r < 4; r++)
        os[(16 * w + 4 * g + r) * 136 + o] = f2bf((acc[ct][r] + bias) * qs);
    }
    __syncthreads();
    #pragma unroll
    for (int i = 0; i < 4; i++){
      int T = tid + 256 * i;
      int row = T >> 4, cb = T & 15;
      *(uint4*)&dst[((size_t)(n * HW) + l0 + row) * CCH + cb * 8] =
          *(const uint4*)&os[row * 136 + cb * 8];
    }
  } else {
    unsigned short* os = (unsigned short*)(lds + 16384);  // [128][72]
    #pragma unroll
    for (int ct = 0; ct < 8; ct++){
      int o = 16 * ct + l15;
      float bias = bsrc[o];
      #pragma unroll
      for (int r = 0; r < 4; r++)
        os[o * 72 + 16 * w + 4 * g + r] = f2bf(acc[ct][r] + bias);
    }
    __syncthreads();
    #pragma unroll
    for (int i = 0; i < 4; i++){
      int T = tid + 256 * i;
      int row = T >> 3, c = T & 7;
      *(uint4*)&Vt[((size_t)(n * CCH) + row) * HW + l0 + c * 8] =
          *(const uint4*)&os[row * 72 + c * 8];
    }
  }
}

// ---------- Kernel D: flash attention, 32-kv tiles, LDS dbuf, 1 barrier ----
// Swapped-operand: QK^T = mfma(K,Q), softmax in-lane, P in regs (8 bpermute),
// PV = mfma(V^T, P). 2 x 16KB K/V buffers = 32KB -> 4 blocks/CU.
__global__ __launch_bounds__(256, 4) void attn_k(const unsigned short* __restrict__ Qg,
    const unsigned short* __restrict__ Kg, const unsigned short* __restrict__ Vt,
    unsigned short* __restrict__ Op, float* __restrict__ Ml, int lsp){
  // chunked bijective XCD swizzle; decode (q fastest, sp, n)
  int nbk = gridDim.x, cpx = nbk >> 3, b = blockIdx.x;
  int swz = (b & 7) * cpx + (b >> 3);
  int q0 = (swz & 63) * 64;
  int rest = swz >> 6;
  int splits = 1 << lsp;
  int sp = rest & (splits - 1);
  int n = rest >> lsp;
  int kvs = HW >> lsp;
  int nt = kvs >> 5;                 // 32-kv tiles
  int tid = threadIdx.x;
  int w = tid >> 6, lane = tid & 63, l15 = lane & 15, g = lane >> 4;
  __shared__ __align__(16) char lds[32768];   // 2 x (K 8KB + V 8KB)

  bf16x8 qf[4];   // lane holds Q[q=16w+l15][c=32kc+8g..]
  #pragma unroll
  for (int kc = 0; kc < 4; kc++)
    qf[kc] = *reinterpret_cast<const bf16x8*>(
        &Qg[((size_t)(n * HW) + q0 + 16 * w + l15) * CCH + 32 * kc + 8 * g]);
  f32x4 ov[8];    // ov[ct][r] = O[q][c=16ct+4g+r] (unnormalized)
  #pragma unroll
  for (int i = 0; i < 8; i++) ov[i] = (f32x4)(0.f);
  float mrun = -3.0e38f, lrun = 0.f;

  // per-lane pre-swizzled global source pointers (2 K-chunks + 2 V-chunks)
  const char* kp[2]; const char* vp[2];
  {
    const char* kbase = (const char*)Kg + ((size_t)(n * HW) + sp * kvs) * (CCH * 2);
    const char* vbase = (const char*)Vt + (size_t)(n * CCH) * (HW * 2) + (size_t)sp * kvs * 2;
    #pragma unroll
    for (int i = 0; i < 2; i++){
      int C = (w * 2 + i) * 64 + lane;            // 0..511 16B-chunks
      int kr = C >> 4, ks = (C & 15) ^ (kr & 15); // K: 16 chunks/row, rows 0..31
      kp[i] = kbase + kr * 256 + ks * 16;
      int vr = C >> 2, vsl = (C & 3) ^ ((vr >> 1) & 3); // V: 4 chunks/row, rows 0..127
      vp[i] = vbase + (size_t)vr * (HW * 2) + vsl * 16;
    }
  }

  // prologue: stage tile 0 into buffer 0
  #pragma unroll
  for (int i = 0; i < 2; i++){
    gll16(kp[i], lds + w * 2048 + i * 1024);
    gll16(vp[i], lds + 8192 + w * 2048 + i * 1024);
  }
  __syncthreads();

  for (int t = 0; t < nt; t++){
    char* cur = lds + ((t & 1) << 14);
    if (t + 1 < nt){   // prefetch next tile into other buffer (covered by compute)
      char* nb = lds + (((t + 1) & 1) << 14);
      #pragma unroll
      for (int i = 0; i < 2; i++){
        gll16(kp[i] + (size_t)(t + 1) * 8192, nb + w * 2048 + i * 1024);
        gll16(vp[i] + (size_t)(t + 1) * 64,   nb + 8192 + w * 2048 + i * 1024);
      }
    }
    char* Ks = cur; char* Vs = cur + 8192;

    // S^T: s[ct][r] = S[q=l15(+16w)][kv=16ct+4g+r], ct=0..1 (32 kv)
    f32x4 s[2];
    __builtin_amdgcn_s_setprio(1);
    #pragma unroll
    for (int ct = 0; ct < 2; ct++){
      f32x4 acc = (f32x4)(0.f);
      #pragma unroll
      for (int kc = 0; kc < 4; kc++){
        bf16x8 kf = *(const bf16x8*)(Ks + (16 * ct + l15) * 256 + (((4 * kc + g) ^ l15) << 4));
        acc = mfma16(kf, qf[kc], acc);
      }
      s[ct] = acc;
    }
    __builtin_amdgcn_s_setprio(0);

    // in-lane softmax (8 scores) + 2-shfl reduce
    float mx = fmaxf(fmaxf(fmaxf(s[0][0], s[0][1]), fmaxf(s[0][2], s[0][3])),
                     fmaxf(fmaxf(s[1][0], s[1][1]), fmaxf(s[1][2], s[1][3])));
    mx = fmaxf(mx, __shfl_xor(mx, 16));
    mx = fmaxf(mx, __shfl_xor(mx, 32));
    if (__any(mx > mrun + 8.0f)){    // defer-rescale (THR=8)
      float mn = fmaxf(mrun, mx);
      float al = __expf(mrun - mn);
      mrun = mn; lrun *= al;
      #pragma unroll
      for (int ct = 0; ct < 8; ct++)
        #pragma unroll
        for (int r = 0; r < 4; r++) ov[ct][r] *= al;
    }
    float rs = 0.f;
    #pragma unroll
    for (int ct = 0; ct < 2; ct++)
      #pragma unroll
      for (int r = 0; r < 4; r++){
        float e = __expf(s[ct][r] - mrun);
        s[ct][r] = e;
        rs += e;
      }
    rs += __shfl_xor(rs, 16);
    rs += __shfl_xor(rs, 32);
    lrun += rs;

    // pack: up[ct][h] = bf16 pair (8ct+2g+h) of this q-row
    unsigned up[2][2];
    #pragma unroll
    for (int ct = 0; ct < 2; ct++)
      #pragma unroll
      for (int h = 0; h < 2; h++)
        up[ct][h] = (unsigned)f2bf(s[ct][2 * h]) |
                    ((unsigned)f2bf(s[ct][2 * h + 1]) << 16);
    // redistribute to B-operand: slot j = kv pair 4g+j; src pair p=4g+j lives
    // at lane g_s=((4(g&1)+j)>>1), reg up[g>>1][j&1]
    union { unsigned u[4]; bf16x8 v; } pb;
    #pragma unroll
    for (int j = 0; j < 4; j++){
      int src = (((((g & 1) << 2) + j) >> 1) << 4) + l15;
      unsigned v0 = (unsigned)__shfl((int)up[0][j & 1], src);
      unsigned v1 = (unsigned)__shfl((int)up[1][j & 1], src);
      pb.u[j] = (g & 2) ? v1 : v0;
    }

    // O^T += V^T P : vf rows = c, k = 32 kv (single mfma per ct)
    __builtin_amdgcn_s_setprio(1);
    #pragma unroll
    for (int ct = 0; ct < 8; ct++){
      int row = 16 * ct + l15;
      bf16x8 vf = *(const bf16x8*)(Vs + row * 64 + ((g ^ ((row >> 1) & 3)) << 4));
      ov[ct] = mfma16(vf, pb.v, ov[ct]);
    }
    __builtin_amdgcn_s_setprio(0);
    __syncthreads();   // drains prefetch glls; hands buffers over
  }
  // epilogue: unnormalized O~ + (m, l)
  size_t obase = (size_t)((sp * NB + n) * HW);
  size_t qrow = obase + q0 + 16 * w + l15;
  #pragma unroll
  for (int ct = 0; ct < 8; ct++){
    ushort4 pk;
    pk.x = f2bf(ov[ct][0]); pk.y = f2bf(ov[ct][1]);
    pk.z = f2bf(ov[ct][2]); pk.w = f2bf(ov[ct][3]);
    *(ushort4*)&Op[qrow * CCH + 16 * ct + 4 * g] = pk;
  }
  if (g == 0){
    Ml[qrow * 2]     = mrun;
    Ml[qrow * 2 + 1] = lrun;
  }
}

// ---------- Kernel E: combine splits + output projection + residual ----------
__global__ __launch_bounds__(256) void projout_k(const unsigned short* __restrict__ Op,
    const float* __restrict__ Ml, const unsigned short* __restrict__ wpb,
    const float* __restrict__ bp, const float* __restrict__ x,
    float* __restrict__ out, int splits){
  int n = blockIdx.y, l0 = blockIdx.x * 32, tid = threadIdx.x;
  int w = tid >> 6, lane = tid & 63, l15 = lane & 15, g = lane >> 4;
  __shared__ __align__(16) unsigned short hs[32][136];
  __shared__ __align__(16) char WB[32768];
  {
    const char* wb2 = (const char*)wpb;
    #pragma unroll
    for (int i = 0; i < 8; i++){
      int T = (8 * w + i) * 64 + lane;
      int row = T >> 4, c16 = (T & 15) ^ (row & 15);
      gll16(wb2 + row * 256 + c16 * 16, WB + (8 * w + i) * 1024);
    }
  }
  const size_t SSTR = (size_t)NB * HW;
  #pragma unroll
  for (int i = 0; i < 2; i++){
    int T = tid + 256 * i;
    int row = T >> 4, cb = (T & 15) * 8;
    size_t gl = (size_t)n * HW + l0 + row;
    float mv = -3.0e38f;
    #pragma unroll
    for (int s = 0; s < 4; s++)
      if (s < splits) mv = fmaxf(mv, Ml[(s * SSTR + gl) * 2]);
    float fa[8];
    #pragma unroll
    for (int j = 0; j < 8; j++) fa[j] = 0.f;
    float denom = 0.f;
    #pragma unroll
    for (int s = 0; s < 4; s++){
      if (s < splits){
        float wgt = __expf(Ml[(s * SSTR + gl) * 2] - mv);
        denom += wgt * Ml[(s * SSTR + gl) * 2 + 1];
        uint4 a = *(const uint4*)&Op[(s * SSTR + gl) * CCH + cb];
        const unsigned short* au = (const unsigned short*)&a;
        #pragma unroll
        for (int j = 0; j < 8; j++) fa[j] += wgt * bf2f(au[j]);
      }
    }
    float inv = 1.f / denom;
    #pragma unroll
    for (int j = 0; j < 8; j++) hs[row][cb + j] = f2bf(fa[j] * inv);
  }
  __syncthreads();
  int rt = w & 1, cg = w >> 1;
  bf16x8 a[4];
  #pragma unroll
  for (int kc = 0; kc < 4; kc++)
    a[kc] = *reinterpret_cast<const bf16x8*>(&hs[16 * rt + l15][32 * kc + 8 * g]);
  f32x4 acc[4];
  #pragma unroll
  for (int ci = 0; ci < 4; ci++) acc[ci] = (f32x4)(0.f);
  #pragma unroll
  for (int ci = 0; ci < 4; ci++){
    int o = 16 * (cg * 4 + ci) + l15;
    #pragma unroll
    for (int kc = 0; kc < 4; kc++){
      bf16x8 bfr = *(const bf16x8*)(WB + o * 256 + ((4 * kc + g) ^ l15) * 16);
      acc[ci] = mfma16(a[kc], bfr, acc[ci]);
    }
  }
  #pragma unroll
  for (int ci = 0; ci < 4; ci++){
    int o = 16 * (cg * 4 + ci) + l15;
    float bias = bp[o];
    size_t base = ((size_t)(n * CCH) + o) * HW + l0 + 16 * rt + 4 * g;
    float4 xr = *(const float4*)&x[base];
    float4 res;
    res.x = xr.x + acc[ci][0] + bias;
    res.y = xr.y + acc[ci][1] + bias;
    res.z = xr.z + acc[ci][2] + bias;
    res.w = xr.w + acc[ci][3] + bias;
    *(float4*)&out[base] = res;
  }
}

extern "C" void kernel_launch(void* const* d_in, const int* in_sizes, int n_in,
                              void* d_out, int out_size, void* d_ws, size_t ws_size,
                              hipStream_t stream){
  const float* x    = (const float*)d_in[0];
  const float* gnsc = (const float*)d_in[1];
  const float* gnb  = (const float*)d_in[2];
  const float* wq   = (const float*)d_in[3];
  const float* bq   = (const float*)d_in[4];
  const float* wk   = (const float*)d_in[5];
  const float* bk   = (const float*)d_in[6];
  const float* wv   = (const float*)d_in[7];
  const float* bv   = (const float*)d_in[8];
  const float* wp   = (const float*)d_in[9];
  const float* bp   = (const float*)d_in[10];
  float* out = (float*)d_out;

  char* ws = (char*)d_ws;
  const size_t BUF = (size_t)NB * HW * CCH * sizeof(unsigned short);  // 4 MiB
  const size_t WOFF = 4096;
  const size_t QOFF = WOFF + 4 * 32768;   // after 4 bf16 weight mats
  const size_t NEED4 = QOFF + 7 * BUF + (size_t)4 * NB * HW * 2 * sizeof(float);
  const int lsp = (ws_size >= NEED4) ? 2 : 1;
  const int splits = 1 << lsp;

  float* stats        = (float*)ws;
  unsigned short* wqb = (unsigned short*)(ws + WOFF);
  unsigned short* wkb = (unsigned short*)(ws + WOFF + 32768);
  unsigned short* wvb = (unsigned short*)(ws + WOFF + 65536);
  unsigned short* wpb = (unsigned short*)(ws + WOFF + 98304);
  unsigned short* Qg  = (unsigned short*)(ws + QOFF);
  unsigned short* Kg  = (unsigned short*)(ws + QOFF + BUF);
  unsigned short* Vt  = (unsigned short*)(ws + QOFF + 2 * BUF);
  unsigned short* Op  = (unsigned short*)(ws + QOFF + 3 * BUF);
  float*          Ml  = (float*)(ws + QOFF + 3 * BUF + (size_t)splits * BUF);

  gn_stats_k<<<128, 256, 0, stream>>>(x, stats, wq, wk, wv, wp, wqb, wkb, wvb, wpb);
  gnqkv_k<<<dim3(64, NB, 3), 256, 0, stream>>>(x, stats, gnsc, gnb,
      wqb, wkb, wvb, bq, bk, bv, Qg, Kg, Vt);
  attn_k<<<dim3(64 * NB * splits), 256, 0, stream>>>(Qg, Kg, Vt, Op, Ml, lsp);
  projout_k<<<dim3(128, NB), 256, 0, stream>>>(Op, Ml, wpb, bp, x, out, splits);
}